// Round 2
// baseline (558.561 us; speedup 1.0000x reference)
//
#include <hip/hip_runtime.h>
#include <math.h>

#define VV 50257
#define Dm 128
#define NN 256
#define RESN 4096
#define SEQ 512
#define TOK 1024  // B*S

using f32x4_t = __attribute__((ext_vector_type(4))) float;
using s16x8_t = __attribute__((ext_vector_type(8))) short;
using u16x4_t = __attribute__((ext_vector_type(4))) unsigned short;
using u16x8_t = __attribute__((ext_vector_type(8))) unsigned short;

static __device__ __forceinline__ unsigned short f2bf(float f) {
    unsigned u = __builtin_bit_cast(unsigned, f);
    u += 0x7fffu + ((u >> 16) & 1u);
    return (unsigned short)(u >> 16);
}

// ---------------- pack: invwl/Bp/ac/as float4 tables, transposed cw/opr/opi, LUT ----------------
__global__ void pack_kernel(const float* __restrict__ W, const float* __restrict__ Bp,
                            const float* __restrict__ ac, const float* __restrict__ as_,
                            const float* __restrict__ cw, const float* __restrict__ opr,
                            const float* __restrict__ opi,
                            float4* __restrict__ packed, float* __restrict__ cwT,
                            float* __restrict__ oprT, float* __restrict__ opiT,
                            float2* __restrict__ lutg) {
    int tid = blockIdx.x * 256 + threadIdx.x;  // 0..65535
    int l = tid >> 15;
    int rem = tid & 32767;
    {   // packed[l][d][n]
        int d = rem >> 8, n = rem & 255;
        int src = (l * NN + n) * Dm + d;
        float4 pk;
        pk.x = 1.0f / (1.0f + fabsf(W[src]));
        pk.y = Bp[src];
        pk.z = ac[src];
        pk.w = as_[src];
        packed[tid] = pk;
    }
    {   // cwT[l][k][d] = cw[l][d][k]
        int k = rem >> 7, d = rem & 127;
        cwT[tid] = cw[(l * Dm + d) * (2 * Dm) + k];
    }
    {   // oprT[l][n][d] = opr[l][d][n]
        int n = rem >> 7, d = rem & 127;
        oprT[tid] = opr[(l * Dm + d) * NN + n];
        opiT[tid] = opi[(l * Dm + d) * NN + n];
    }
    if (tid < RESN) {
        float ang = (float)tid * (float)(6.283185307179586476925286766559 / 4096.0);
        lutg[tid] = make_float2(sinf(ang), cosf(ang));
    }
}

// ---------------- embedding gather: x[t][0:256] = emb[ids[t]] ----------------
__global__ void embed_kernel(const int* __restrict__ ids, const float* __restrict__ emb,
                             float* __restrict__ x) {
    int t = blockIdx.x;
    int k = threadIdx.x;
    x[t * 256 + k] = emb[(size_t)ids[t] * 256 + k];
}

// ---------------- xc = x @ cw[l].T + cb[l] : (1024 x 128), K=256 ----------------
__global__ void xc_kernel(const float* __restrict__ x, const float* __restrict__ cwT,
                          const float* __restrict__ cb, float* __restrict__ xc, int l) {
    __shared__ float xs[2][256];
    int tid = threadIdx.x;
    int t0 = blockIdx.x * 2;
    xs[0][tid] = x[t0 * 256 + tid];
    xs[1][tid] = x[(t0 + 1) * 256 + tid];
    __syncthreads();
    int j = tid >> 7, d = tid & 127;
    const float* cwb = cwT + l * 32768;
    float acc = 0.f;
#pragma unroll 8
    for (int k = 0; k < 256; k++) acc = fmaf(xs[j][k], cwb[k * 128 + d], acc);
    xc[(t0 + j) * 128 + d] = acc + cb[l * 128 + d];
}

// ---------------- theta/LUT/reduce over d: partial cos_sum/sin_sum ----------------
// grid (256 token-groups of 4, 2 d-halves); thread = n
__global__ void __launch_bounds__(256) theta_kernel(const float* __restrict__ xc,
                                                    const float4* __restrict__ packed,
                                                    const float2* __restrict__ lutg,
                                                    float* __restrict__ pr_part,
                                                    float* __restrict__ pi_part, int l) {
    __shared__ float2 lut[RESN];
    __shared__ float xcs[4][64];
    int tid = threadIdx.x;
    int t0 = blockIdx.x * 4;
    int dh = blockIdx.y;
    // copy LUT global->LDS (float4 = 2 entries)
    const float4* lg = (const float4*)lutg;
    float4* ldst = (float4*)lut;
#pragma unroll
    for (int i = 0; i < 8; i++) ldst[tid + i * 256] = lg[tid + i * 256];
    {
        int j = tid >> 6, i = tid & 63;
        xcs[j][i] = xc[(t0 + j) * 128 + dh * 64 + i];
    }
    __syncthreads();
    float tv[4];
#pragma unroll
    for (int j = 0; j < 4; j++) {
        int s = (t0 + j) & (SEQ - 1);
        tv[j] = (float)s * 1.61803398874989485f;  // PHI
    }
    const float4* pk = packed + ((size_t)(l * Dm + dh * 64)) * NN + tid;
    float cs[4] = {0, 0, 0, 0}, sn[4] = {0, 0, 0, 0};
    const float SC = (float)(4096.0 / 6.283185307179586476925286766559);
    for (int d = 0; d < 64; d += 4) {
        // 4 packed loads in flight (latency hiding)
        float4 p0 = pk[(size_t)(d + 0) * NN];
        float4 p1 = pk[(size_t)(d + 1) * NN];
        float4 p2 = pk[(size_t)(d + 2) * NN];
        float4 p3 = pk[(size_t)(d + 3) * NN];
#pragma unroll
        for (int dd = 0; dd < 4; dd++) {
            float4 p = (dd == 0) ? p0 : (dd == 1) ? p1 : (dd == 2) ? p2 : p3;
            float xv0 = xcs[0][d + dd], xv1 = xcs[1][d + dd];
            float xv2 = xcs[2][d + dd], xv3 = xcs[3][d + dd];
            float th;
            int idx;
            float2 scv;
            th = fmaf(xv0, p.x, p.y) + tv[0];
            idx = ((int)floorf(th * SC)) & (RESN - 1);
            scv = lut[idx];
            cs[0] = fmaf(scv.y, p.z, cs[0]);
            sn[0] = fmaf(scv.x, p.w, sn[0]);
            th = fmaf(xv1, p.x, p.y) + tv[1];
            idx = ((int)floorf(th * SC)) & (RESN - 1);
            scv = lut[idx];
            cs[1] = fmaf(scv.y, p.z, cs[1]);
            sn[1] = fmaf(scv.x, p.w, sn[1]);
            th = fmaf(xv2, p.x, p.y) + tv[2];
            idx = ((int)floorf(th * SC)) & (RESN - 1);
            scv = lut[idx];
            cs[2] = fmaf(scv.y, p.z, cs[2]);
            sn[2] = fmaf(scv.x, p.w, sn[2]);
            th = fmaf(xv3, p.x, p.y) + tv[3];
            idx = ((int)floorf(th * SC)) & (RESN - 1);
            scv = lut[idx];
            cs[3] = fmaf(scv.y, p.z, cs[3]);
            sn[3] = fmaf(scv.x, p.w, sn[3]);
        }
    }
#pragma unroll
    for (int j = 0; j < 4; j++) {
        pr_part[(size_t)(dh * TOK + t0 + j) * NN + tid] = cs[j];
        pi_part[(size_t)(dh * TOK + t0 + j) * NN + tid] = sn[j];
    }
}

// ---------------- out-proj: x_new = silu(sum @ op.T), writes [xr|xi] layout ----------------
__global__ void proj_kernel(const float* __restrict__ pr_part, const float* __restrict__ pi_part,
                            const float* __restrict__ oprT, const float* __restrict__ opiT,
                            float* __restrict__ x, int l) {
    __shared__ float prs[4][256], pis[4][256];
    int tid = threadIdx.x;
    int t0 = blockIdx.x * 4;
#pragma unroll
    for (int i = 0; i < 4; i++) {
        prs[i][tid] = pr_part[(size_t)(t0 + i) * 256 + tid] +
                      pr_part[(size_t)(TOK + t0 + i) * 256 + tid];
        pis[i][tid] = pi_part[(size_t)(t0 + i) * 256 + tid] +
                      pi_part[(size_t)(TOK + t0 + i) * 256 + tid];
    }
    __syncthreads();
    int g = tid >> 7, d = tid & 127;
    const float* wb = (g == 0 ? oprT : opiT) + l * 32768;
    const float(*ps)[256] = (g == 0) ? prs : pis;
    float acc[4] = {0, 0, 0, 0};
#pragma unroll 4
    for (int n = 0; n < 256; n++) {
        float wv = wb[n * 128 + d];
#pragma unroll
        for (int j = 0; j < 4; j++) acc[j] = fmaf(ps[j][n], wv, acc[j]);
    }
#pragma unroll
    for (int j = 0; j < 4; j++) {
        float v = acc[j];
        float s = v / (1.0f + expf(-v));  // silu
        x[(t0 + j) * 256 + g * 128 + d] = s;
    }
}

// ---------------- xconv: x fp32 -> MFMA-A-fragment-major bf16 ----------------
// entry e = (tb*8 + ks)*64 + lane holds x[tb*16 + (lane&15)][ks*32 + (lane>>4)*8 .. +7]
__global__ void xconv_kernel(const float* __restrict__ x, unsigned short* __restrict__ xf) {
    int e = blockIdx.x * 256 + threadIdx.x;  // 0..32767
    int lane = e & 63;
    int ks = (e >> 6) & 7;
    int tb = e >> 9;
    int row = tb * 16 + (lane & 15);
    int col = ks * 32 + (lane >> 4) * 8;
    const float4* s4 = (const float4*)(x + (size_t)row * 256 + col);
    float4 a = s4[0], b = s4[1];
    u16x8_t pkt = {f2bf(a.x), f2bf(a.y), f2bf(a.z), f2bf(a.w),
                   f2bf(b.x), f2bf(b.y), f2bf(b.z), f2bf(b.w)};
    *(u16x8_t*)(xf + (size_t)e * 8) = pkt;
}

// ---------------- final complex GEMM + magnitude (weight-stationary) ----------------
// One block per 64-v tile. B1=[Wr|-Wi], B2=[Wi|Wr] staged ONCE into LDS in
// MFMA-B-fragment-major order (pad 1 entry per 16 to break 256B aliasing).
// 8 waves: wave&3 = v-subtile (16 v), wave>>2 = t-half. No barriers in main loop.
__global__ void __launch_bounds__(512, 4) final_kernel(const unsigned short* __restrict__ xf,
                                                       const float* __restrict__ Wr,
                                                       const float* __restrict__ Wi,
                                                       float* __restrict__ out) {
    __shared__ unsigned short B1s[32 * 68 * 8];  // 32 groups x 68 entries x 16B = 34816 B
    __shared__ unsigned short B2s[32 * 68 * 8];
    int tid = threadIdx.x;
    int v0 = blockIdx.x * 64;

    // ---- stage B (once) ----
#pragma unroll
    for (int it = 0; it < 2; it++) {
        int idx = tid + it * 512;        // 0..1023 = 64 rows x 16 k8-chunks
        int row = idx >> 4, k8 = idx & 15;
        int k = k8 * 8;                  // 0..127
        int v = v0 + row;
        if (v >= VV) v = VV - 1;
        const float4* wr4 = (const float4*)(Wr + (size_t)v * 128 + k);
        const float4* wi4 = (const float4*)(Wi + (size_t)v * 128 + k);
        float4 ra = wr4[0], rb = wr4[1];
        float4 ia = wi4[0], ib = wi4[1];
        u16x8_t wr8 = {f2bf(ra.x), f2bf(ra.y), f2bf(ra.z), f2bf(ra.w),
                       f2bf(rb.x), f2bf(rb.y), f2bf(rb.z), f2bf(rb.w)};
        u16x8_t wi8 = {f2bf(ia.x), f2bf(ia.y), f2bf(ia.z), f2bf(ia.w),
                       f2bf(ib.x), f2bf(ib.y), f2bf(ib.z), f2bf(ib.w)};
        u16x8_t wn8 = {f2bf(-ia.x), f2bf(-ia.y), f2bf(-ia.z), f2bf(-ia.w),
                       f2bf(-ib.x), f2bf(-ib.y), f2bf(-ib.z), f2bf(-ib.w)};
        int lanehi = (k & 31) >> 3;
        int lane = lanehi * 16 + (row & 15);
        int gl = (row >> 4) * 8 + (k >> 5);      // k in [0,128)
        int gh = gl + 4;                         // k+128 in [128,256)
        int el = gl * 68 + lane + lanehi;
        int eh = gh * 68 + lane + lanehi;
        *(u16x8_t*)(B1s + el * 8) = wr8;  // k<128:  B1 = Wr
        *(u16x8_t*)(B2s + el * 8) = wi8;  //         B2 = Wi
        *(u16x8_t*)(B1s + eh * 8) = wn8;  // k>=128: B1 = -Wi
        *(u16x8_t*)(B2s + eh * 8) = wr8;  //         B2 = Wr
    }
    __syncthreads();

    // ---- main loop: all 1024 tokens, no barriers ----
    int wave = tid >> 6, lane = tid & 63;
    int sub = wave & 3, half = wave >> 2;
    int quad = lane >> 4, t16 = lane & 15;
    int bperm = lane + (lane >> 4);  // padded fragment entry index
    int vstore = v0 + sub * 16 + t16;
    bool vok = vstore < VV;

    for (int ii = 0; ii < 8; ii++) {
        int i = half * 8 + ii;  // t-chunk of 64 tokens: t0 = i*64
        f32x4_t accR[4], accI[4];
#pragma unroll
        for (int m = 0; m < 4; m++) {
            accR[m] = (f32x4_t){0.f, 0.f, 0.f, 0.f};
            accI[m] = (f32x4_t){0.f, 0.f, 0.f, 0.f};
        }
#pragma unroll
        for (int ks = 0; ks < 8; ks++) {
            s16x8_t a0 = *(const s16x8_t*)(xf + ((size_t)((i * 4 + 0) * 8 + ks) * 64 + lane) * 8);
            s16x8_t a1 = *(const s16x8_t*)(xf + ((size_t)((i * 4 + 1) * 8 + ks) * 64 + lane) * 8);
            s16x8_t a2 = *(const s16x8_t*)(xf + ((size_t)((i * 4 + 2) * 8 + ks) * 64 + lane) * 8);
            s16x8_t a3 = *(const s16x8_t*)(xf + ((size_t)((i * 4 + 3) * 8 + ks) * 64 + lane) * 8);
            s16x8_t b1 = *(const s16x8_t*)(B1s + ((sub * 8 + ks) * 68 + bperm) * 8);
            s16x8_t b2 = *(const s16x8_t*)(B2s + ((sub * 8 + ks) * 68 + bperm) * 8);
            accR[0] = __builtin_amdgcn_mfma_f32_16x16x32_bf16(a0, b1, accR[0], 0, 0, 0);
            accI[0] = __builtin_amdgcn_mfma_f32_16x16x32_bf16(a0, b2, accI[0], 0, 0, 0);
            accR[1] = __builtin_amdgcn_mfma_f32_16x16x32_bf16(a1, b1, accR[1], 0, 0, 0);
            accI[1] = __builtin_amdgcn_mfma_f32_16x16x32_bf16(a1, b2, accI[1], 0, 0, 0);
            accR[2] = __builtin_amdgcn_mfma_f32_16x16x32_bf16(a2, b1, accR[2], 0, 0, 0);
            accI[2] = __builtin_amdgcn_mfma_f32_16x16x32_bf16(a2, b2, accI[2], 0, 0, 0);
            accR[3] = __builtin_amdgcn_mfma_f32_16x16x32_bf16(a3, b1, accR[3], 0, 0, 0);
            accI[3] = __builtin_amdgcn_mfma_f32_16x16x32_bf16(a3, b2, accI[3], 0, 0, 0);
        }
        // epilogue: C/D col=lane&15 -> v, row=quad*4+r -> t
        if (vok) {
            int tbase = i * 64 + quad * 4;
#pragma unroll
            for (int m = 0; m < 4; m++) {
#pragma unroll
                for (int r = 0; r < 4; r++) {
                    float lr = accR[m][r];
                    float li = accI[m][r];
                    out[(size_t)(tbase + m * 16 + r) * VV + vstore] =
                        sqrtf(fmaf(lr, lr, fmaf(li, li, 1e-8f)));
                }
            }
        }
    }
}

extern "C" void kernel_launch(void* const* d_in, const int* in_sizes, int n_in,
                              void* d_out, int out_size, void* d_ws, size_t ws_size,
                              hipStream_t stream) {
    const int* ids   = (const int*)d_in[0];
    const float* emb = (const float*)d_in[1];
    const float* cw  = (const float*)d_in[2];
    const float* cb  = (const float*)d_in[3];
    const float* W   = (const float*)d_in[4];
    const float* Bp  = (const float*)d_in[5];
    const float* ac  = (const float*)d_in[6];
    const float* as_ = (const float*)d_in[7];
    const float* opr = (const float*)d_in[8];
    const float* opi = (const float*)d_in[9];
    const float* Wr  = (const float*)d_in[10];
    const float* Wi  = (const float*)d_in[11];
    float* out = (float*)d_out;

    char* ws = (char*)d_ws;
    float*  x       = (float*)(ws);                          // 1 MB (1024x256)
    float*  xc      = (float*)(ws + (1u << 20));             // 512 KB
    float*  pr_part = (float*)(ws + (2u << 20));             // 2 MB (2x1024x256)
    float*  pi_part = (float*)(ws + (4u << 20));             // 2 MB
    float4* packed  = (float4*)(ws + (6u << 20));            // 1 MB (2x128x256 float4)
    float*  cwT     = (float*)(ws + (7u << 20));             // 256 KB
    float*  oprT    = (float*)(ws + (7u << 20) + (256u << 10));
    float*  opiT    = (float*)(ws + (7u << 20) + (512u << 10));
    float2* lutg    = (float2*)(ws + (7u << 20) + (768u << 10));  // 32 KB
    unsigned short* xfrag = (unsigned short*)(ws + (2u << 20));   // 512 KB, reuses pr_part
                                                                  // (pr/pi dead after last proj)

    pack_kernel<<<256, 256, 0, stream>>>(W, Bp, ac, as_, cw, opr, opi,
                                         packed, cwT, oprT, opiT, lutg);
    embed_kernel<<<TOK, 256, 0, stream>>>(ids, emb, x);
    for (int l = 0; l < 2; l++) {
        xc_kernel<<<TOK / 2, 256, 0, stream>>>(x, cwT, cb, xc, l);
        theta_kernel<<<dim3(TOK / 4, 2), 256, 0, stream>>>(xc, packed, lutg,
                                                           pr_part, pi_part, l);
        proj_kernel<<<TOK / 4, 256, 0, stream>>>(pr_part, pi_part, oprT, opiT, x, l);
    }
    xconv_kernel<<<128, 256, 0, stream>>>(x, xfrag);
    final_kernel<<<dim3((VV + 63) / 64), 512, 0, stream>>>(xfrag, Wr, Wi, out);
}